// Round 5
// baseline (571.469 us; speedup 1.0000x reference)
//
#include <hip/hip_runtime.h>
#include <hip/hip_bf16.h>

// Problem constants (from reference): B=2, S=2048 -> T=4096 tokens
#define T_TOK 4096
#define DDIM  1024
#define FDIM  512
#define NEXP  16
#define NE17  17       // 16 experts + shared expert as expert 16 (cw=1)
#define MAXTILES 304   // 272 max expert row-tiles + 32 shared; 304 = 8*38 (XCD-exact)

using bf16x8 = __attribute__((ext_vector_type(8))) __bf16;
using f32x4  = __attribute__((ext_vector_type(4))) float;

// ---------------------------------------------------------------------------
// async global->LDS, 16B per lane. LDS dest = wave-uniform base + lane*16;
// global source is per-lane (gather-capable).
__device__ __forceinline__ void gload_lds16(const void* g, void* l) {
  __builtin_amdgcn_global_load_lds(
      (const __attribute__((address_space(1))) void*)g,
      (__attribute__((address_space(3))) void*)l, 16, 0, 0);
}

// XOR-swizzled ds_read_b128 of one MFMA fragment (8 bf16 along K).
// All LDS tiles are [rows][64] bf16 => 128B rows. chunk = 16B unit along K.
__device__ __forceinline__ bf16x8 frag_ld(const __hip_bfloat16* smem, int row, int chunk) {
  const char* p = (const char*)smem + row * 128 + ((chunk ^ (row & 7)) << 4);
  return *(const bf16x8*)p;
}

// ---------------------------------------------------------------------------
// Fused x->bf16 convert + router. One wave per token; x row read ONCE into
// registers, used for both the bf16 store and the 16 router dot products.
// Top-8 via lane-parallel rank (tie-break lower index == jax.lax.top_k).
__global__ void convert_router(const float* __restrict__ x, const float* __restrict__ rw,
                               __hip_bfloat16* __restrict__ xb, float* __restrict__ cw) {
  const int t = blockIdx.x;
  const int lane = threadIdx.x;  // 64
  const float4* xrow = (const float4*)(x + (size_t)t * DDIM);
  float4 v[4];
#pragma unroll
  for (int c = 0; c < 4; c++) v[c] = xrow[lane + 64 * c];
  // bf16 convert + store (8B per lane per chunk, coalesced)
  __hip_bfloat16* orow = xb + (size_t)t * DDIM;
#pragma unroll
  for (int c = 0; c < 4; c++) {
    __hip_bfloat16 h[4] = {__float2bfloat16(v[c].x), __float2bfloat16(v[c].y),
                           __float2bfloat16(v[c].z), __float2bfloat16(v[c].w)};
    *(uint2*)(orow + (lane + 64 * c) * 4) = *(const uint2*)h;
  }
  // router logits (fp32, exact as reference)
  const float4* rw4 = (const float4*)rw;
  float myLg = 0.f;
#pragma unroll
  for (int e = 0; e < NEXP; e++) {
    float p = 0.f;
#pragma unroll
    for (int c = 0; c < 4; c++) {
      const float4 r = rw4[e * 256 + lane + 64 * c];
      p += v[c].x * r.x + v[c].y * r.y + v[c].z * r.z + v[c].w * r.w;
    }
#pragma unroll
    for (int off = 32; off > 0; off >>= 1) p += __shfl_xor(p, off);
    if (lane == e) myLg = p;  // lane e keeps logit e (all lanes have the sum)
  }
  // max over lanes 0..15 (xor 8/4/2/1 closed within the 16-lane group)
  float m = myLg;
#pragma unroll
  for (int off = 8; off > 0; off >>= 1) m = fmaxf(m, __shfl_xor(m, off));
  const float pe = __expf(myLg - m);
  int rank = 0;
#pragma unroll
  for (int j = 0; j < NEXP; j++) {
    const float pj = __shfl(pe, j);
    rank += ((pj > pe) || (pj == pe && j < lane)) ? 1 : 0;
  }
  const bool sel = (lane < NEXP) && (rank < 8);
  float ss = sel ? pe : 0.f;
#pragma unroll
  for (int off = 8; off > 0; off >>= 1) ss += __shfl_xor(ss, off);
  if (lane < NEXP) cw[(size_t)t * NEXP + lane] = sel ? pe / ss : 0.f;
}

// ---------------------------------------------------------------------------
// Token->expert grouping (deterministic): count, scan+tile-map, place.
__global__ void moe_count(const float* __restrict__ cw, int* __restrict__ cnt) {
  const int e = blockIdx.x;  // 0..15
  const int lane = threadIdx.x;
  int c = 0;
  for (int t = lane; t < T_TOK; t += 64) c += (cw[(size_t)t * 16 + e] > 0.f) ? 1 : 0;
#pragma unroll
  for (int off = 32; off > 0; off >>= 1) c += __shfl_xor(c, off);
  if (lane == 0) cnt[e] = c;
}

__global__ void moe_scan(const int* __restrict__ cnt, int* __restrict__ padBase,
                         int* __restrict__ tileE, int* __restrict__ tileBase) {
  if (threadIdx.x != 0) return;
  int base = 0, tile = 0;
  for (int e = 0; e < 16; e++) {
    padBase[e] = base;
    const int nt = (cnt[e] + 127) >> 7;
    for (int i = 0; i < nt; i++) { tileE[tile] = e; tileBase[tile] = base + (i << 7); tile++; }
    base += nt << 7;
  }
  padBase[16] = base;  // shared-expert group base
  for (int i = 0; i < 32; i++) { tileE[tile] = 16; tileBase[tile] = base + (i << 7); tile++; }
  for (; tile < MAXTILES; tile++) tileE[tile] = -1;
}

__global__ void moe_place(const float* __restrict__ cw, const int* __restrict__ cnt,
                          const int* __restrict__ padBase,
                          int* __restrict__ perm, float* __restrict__ rowW) {
  const int e = blockIdx.x;  // 0..16
  const int lane = threadIdx.x;  // one wave
  const int base = padBase[e];
  if (e == 16) {  // shared expert: identity order, weight 1
    for (int t = lane; t < T_TOK; t += 64) { perm[base + t] = t; rowW[base + t] = 1.0f; }
    return;
  }
  int running = 0;
  for (int t0 = 0; t0 < T_TOK; t0 += 64) {
    const int t = t0 + lane;
    const float w = cw[(size_t)t * 16 + e];
    const unsigned long long m = __ballot(w > 0.f);
    if (w > 0.f) {
      const int r = base + running + __popcll(m & ((1ull << lane) - 1ull));
      perm[r] = t; rowW[r] = w;
    }
    running += __popcll(m);
  }
  const int padded = ((cnt[e] + 127) >> 7) << 7;  // cnt[e] == running
  for (int i = running + lane; i < padded; i += 64) { perm[base + i] = -1; rowW[base + i] = 0.f; }
}

// ---------------------------------------------------------------------------
// Transpose-convert gate+up together: in [R][C] fp32 x2 -> out [C][R] bf16 x2.
__global__ __launch_bounds__(256, 4) void transpose_convert2(
    const float* __restrict__ srcMainA, const float* __restrict__ srcSharedA,
    const float* __restrict__ srcMainB, const float* __restrict__ srcSharedB,
    __hip_bfloat16* __restrict__ dstA, __hip_bfloat16* __restrict__ dstB, int R, int C) {
  const int e = blockIdx.z;
  const float* srcA = (e < NEXP) ? srcMainA + (size_t)e * R * C : srcSharedA;
  const float* srcB = (e < NEXP) ? srcMainB + (size_t)e * R * C : srcSharedB;
  __hip_bfloat16* outA = dstA + (size_t)e * R * C;
  __hip_bfloat16* outB = dstB + (size_t)e * R * C;
  __shared__ float tA[64][65];
  __shared__ float tB[64][65];
  const int c0 = blockIdx.x * 64, r0 = blockIdx.y * 64;
  const int tx = threadIdx.x, ty = threadIdx.y;  // 64 x 4
#pragma unroll
  for (int i = 0; i < 64; i += 4) {
    tA[ty + i][tx] = srcA[(size_t)(r0 + ty + i) * C + c0 + tx];
    tB[ty + i][tx] = srcB[(size_t)(r0 + ty + i) * C + c0 + tx];
  }
  __syncthreads();
#pragma unroll
  for (int i = 0; i < 64; i += 4) {
    outA[(size_t)(c0 + ty + i) * R + r0 + tx] = __float2bfloat16(tA[tx][ty + i]);
    outB[(size_t)(c0 + ty + i) * R + r0 + tx] = __float2bfloat16(tB[tx][ty + i]);
  }
}

// Single transpose-convert (down + sd)
__global__ __launch_bounds__(256, 4) void transpose_convert(
    const float* __restrict__ srcMain, const float* __restrict__ srcShared,
    __hip_bfloat16* __restrict__ dst, int R, int C) {
  const int e = blockIdx.z;
  const float* src = (e < NEXP) ? srcMain + (size_t)e * R * C : srcShared;
  __hip_bfloat16* out = dst + (size_t)e * R * C;
  __shared__ float tile[64][65];
  const int c0 = blockIdx.x * 64, r0 = blockIdx.y * 64;
  const int tx = threadIdx.x, ty = threadIdx.y;  // 64 x 4
#pragma unroll
  for (int i = 0; i < 64; i += 4)
    tile[ty + i][tx] = src[(size_t)(r0 + ty + i) * C + c0 + tx];
  __syncthreads();
#pragma unroll
  for (int i = 0; i < 64; i += 4)
    out[(size_t)(c0 + ty + i) * R + r0 + tx] = __float2bfloat16(tile[tx][ty + i]);
}

// ---------------------------------------------------------------------------
// Stage A (grouped/sparse): per expert row-tile (128 gathered tokens) x 128
// f-cols: G = Xg @ Wg[e], U = Xg @ Wu[e] (dual acc, shared gathered X tile),
// H[e][tok][f] = silu(G)*U * rowW. Pad rows (perm<0) load token 0, store nothing.
// 3 blocks/CU (LDS 3x49KB = 150.5KB fits); XCD-chunked tile swizzle.
__global__ __launch_bounds__(256, 3) void moe_stageA_grouped(
    const __hip_bfloat16* __restrict__ xb,   // [T][D]
    const __hip_bfloat16* __restrict__ wg,   // [17][F][D]
    const __hip_bfloat16* __restrict__ wu,   // [17][F][D]
    const int* __restrict__ perm, const float* __restrict__ rowW,
    const int* __restrict__ tileE, const int* __restrict__ tileBase,
    __hip_bfloat16* __restrict__ H)          // [17][T][F] (pre-zeroed)
{
  __shared__ __hip_bfloat16 sA[128 * 64];
  __shared__ __hip_bfloat16 sG[128 * 64];
  __shared__ __hip_bfloat16 sU[128 * 64];
  __shared__ int   sTok[128];
  __shared__ float sW[128];

  // XCD-chunked swizzle: 304 = 8*38; XCD k gets contiguous tiles [38k,38k+38)
  // (same-expert tiles share Wg/Wu panels in that XCD's L2). 304%8==0 -> bijective.
  const int tile = (blockIdx.x & 7) * (MAXTILES / 8) + (blockIdx.x >> 3);
  const int e = tileE[tile];
  if (e < 0) return;
  const int rbase = tileBase[tile];
  const int f0 = blockIdx.y * 128;
  const int tid = threadIdx.x;
  const int wid = tid >> 6, lane = tid & 63;
  const int wr = (wid >> 1) * 64, wc = (wid & 1) * 64;  // wave tile 64x64 (dual)
  const int rl = lane >> 3, cl = lane & 7;

  if (tid < 128) { const int r = rbase + tid; sTok[tid] = perm[r]; sW[tid] = rowW[r]; }
  __syncthreads();

  const __hip_bfloat16* wgE = wg + (size_t)e * FDIM * DDIM;
  const __hip_bfloat16* wuE = wu + (size_t)e * FDIM * DDIM;

  // hoisted per-lane staging pointers (k0-invariant part)
  const char* pA[4]; const char* pG[4]; const char* pU[4]; int ldsO[4];
#pragma unroll
  for (int i = 0; i < 4; i++) {
    const int row = 32 * wid + 8 * i + rl;
    const int sw = (cl ^ (row & 7)) << 3;  // element offset of swizzled 16B chunk
    int tk = sTok[row]; if (tk < 0) tk = 0;
    pA[i] = (const char*)(xb  + (size_t)tk * DDIM + sw);
    pG[i] = (const char*)(wgE + (size_t)(f0 + row) * DDIM + sw);
    pU[i] = (const char*)(wuE + (size_t)(f0 + row) * DDIM + sw);
    ldsO[i] = (32 * wid + 8 * i) * 64;
  }

  const f32x4 vzero = {0.f, 0.f, 0.f, 0.f};
  f32x4 accG[4][4], accU[4][4];
#pragma unroll
  for (int m = 0; m < 4; m++)
#pragma unroll
    for (int n = 0; n < 4; n++) { accG[m][n] = vzero; accU[m][n] = vzero; }

  for (int k0 = 0; k0 < DDIM; k0 += 64) {
    __syncthreads();  // previous iter's reads done before overwrite
#pragma unroll
    for (int i = 0; i < 4; i++) {
      gload_lds16(pA[i] + (size_t)k0 * 2, &sA[ldsO[i]]);
      gload_lds16(pG[i] + (size_t)k0 * 2, &sG[ldsO[i]]);
      gload_lds16(pU[i] + (size_t)k0 * 2, &sU[ldsO[i]]);
    }
    __syncthreads();  // drains vmcnt -> staged data visible
#pragma unroll
    for (int kk = 0; kk < 2; kk++) {
      const int kch = kk * 4 + (lane >> 4);
      bf16x8 af[4], bg[4], bu[4];
#pragma unroll
      for (int m = 0; m < 4; m++) af[m] = frag_ld(sA, wr + m * 16 + (lane & 15), kch);
#pragma unroll
      for (int n = 0; n < 4; n++) {
        bg[n] = frag_ld(sG, wc + n * 16 + (lane & 15), kch);
        bu[n] = frag_ld(sU, wc + n * 16 + (lane & 15), kch);
      }
#pragma unroll
      for (int m = 0; m < 4; m++)
#pragma unroll
        for (int n = 0; n < 4; n++) {
          accG[m][n] = __builtin_amdgcn_mfma_f32_16x16x32_bf16(af[m], bg[n], accG[m][n], 0, 0, 0);
          accU[m][n] = __builtin_amdgcn_mfma_f32_16x16x32_bf16(af[m], bu[n], accU[m][n], 0, 0, 0);
        }
    }
  }
  // epilogue: h = silu(g)*u*rowW -> H[e][tok][:]; pad rows store nothing
  const int lr = (lane >> 4) * 4, lc = lane & 15;
#pragma unroll
  for (int m = 0; m < 4; m++)
#pragma unroll
    for (int n = 0; n < 4; n++)
#pragma unroll
      for (int j = 0; j < 4; j++) {
        const int r = wr + m * 16 + lr + j;
        const int c = wc + n * 16 + lc;
        const int tok = sTok[r];
        if (tok >= 0) {
          const float g = accG[m][n][j], u = accU[m][n][j];
          const float h = (g / (1.0f + __expf(-g))) * u * sW[r];
          H[((size_t)e * T_TOK + tok) * FDIM + f0 + c] = __float2bfloat16(h);
        }
      }
}

// ---------------------------------------------------------------------------
// Stage B (K-split x3, single-buffered m97 structure): out[t][d] = sum over
// K=17*512 of H[e][t][f]*Wd_t[e][d][f]. 32KB LDS -> 4 blocks/CU for TLP.
// split 0 -> p0, split 1 -> p1, split 2 -> out; then out += p0 + p1.
__global__ __launch_bounds__(256, 4) void moe_stageB_split(
    const __hip_bfloat16* __restrict__ H,    // [17][T][F]
    const __hip_bfloat16* __restrict__ wd,   // [17][D][F]
    float* __restrict__ out,                 // [T][D]
    float* __restrict__ p0, float* __restrict__ p1)
{
  __shared__ __hip_bfloat16 sA[128 * 64];
  __shared__ __hip_bfloat16 sB[128 * 64];

  // XCD-chunked mapping: XCD k owns t-tiles [4k,4k+4) x all 8 d-tiles
  const int id = blockIdx.x;            // 0..255, id&7 = XCD (round-robin dispatch)
  const int xcd = id & 7, slot = id >> 3;
  const int t0 = (xcd * 4 + (slot & 3)) * 128;
  const int d0 = (slot >> 2) * 128;
  const int tid = threadIdx.x, wid = tid >> 6, lane = tid & 63;
  const int wr = (wid >> 1) * 64, wc = (wid & 1) * 64;  // wave tile 64x64
  const int rl = lane >> 3, cl = lane & 7;

  // hoisted per-lane staging offsets (k0-invariant row part)
  size_t offA[4], offB[4]; int ldsO[4];
#pragma unroll
  for (int i = 0; i < 4; i++) {
    const int row = 32 * wid + 8 * i + rl;
    const int sw = (cl ^ (row & 7)) << 3;
    offA[i] = (size_t)(t0 + row) * FDIM + sw;
    offB[i] = (size_t)(d0 + row) * FDIM + sw;
    ldsO[i] = (32 * wid + 8 * i) * 64;
  }

  const f32x4 vzero = {0.f, 0.f, 0.f, 0.f};
  f32x4 acc[4][4];
#pragma unroll
  for (int m = 0; m < 4; m++)
#pragma unroll
    for (int n = 0; n < 4; n++) acc[m][n] = vzero;

  const int NKS = NE17 * FDIM / 64;  // 136 total K-steps
  const int split = blockIdx.y;      // 0..2 -> steps [45,45,46]
  const int ks0 = (split * NKS) / 3, ks1 = ((split + 1) * NKS) / 3;

  for (int ks = ks0; ks < ks1; ks++) {
    const int k0 = ks * 64;
    const int ee = k0 >> 9, ff = k0 & 511;  // FDIM=512 | 64 => no straddle
    const size_t sOffA = (size_t)ee * T_TOK * FDIM + ff;
    const size_t sOffB = (size_t)ee * DDIM * FDIM + ff;
    __syncthreads();  // previous iter's reads done before overwrite
#pragma unroll
    for (int i = 0; i < 4; i++) {
      gload_lds16(H  + sOffA + offA[i], &sA[ldsO[i]]);
      gload_lds16(wd + sOffB + offB[i], &sB[ldsO[i]]);
    }
    __syncthreads();  // drains vmcnt: staged data visible
#pragma unroll
    for (int kk = 0; kk < 2; kk++) {
      const int kch = kk * 4 + (lane >> 4);
      bf16x8 af[4], bb[4];
#pragma unroll
      for (int m = 0; m < 4; m++) af[m] = frag_ld(sA, wr + m * 16 + (lane & 15), kch);
#pragma unroll
      for (int n = 0; n < 4; n++) bb[n] = frag_ld(sB, wc + n * 16 + (lane & 15), kch);
#pragma unroll
      for (int m = 0; m < 4; m++)
#pragma unroll
        for (int n = 0; n < 4; n++)
          acc[m][n] = __builtin_amdgcn_mfma_f32_16x16x32_bf16(af[m], bb[n], acc[m][n], 0, 0, 0);
    }
  }
  float* dst = (split == 0) ? p0 : (split == 1) ? p1 : out;
  const int lr = (lane >> 4) * 4, lc = lane & 15;
#pragma unroll
  for (int m = 0; m < 4; m++)
#pragma unroll
    for (int n = 0; n < 4; n++)
#pragma unroll
      for (int j = 0; j < 4; j++)
        dst[(size_t)(t0 + wr + m * 16 + lr + j) * DDIM + d0 + wc + n * 16 + lc] = acc[m][n][j];
}

// out += p0 + p1 (float4)
__global__ void add_partial(float* __restrict__ out, const float* __restrict__ p0,
                            const float* __restrict__ p1, int n4) {
  int i = blockIdx.x * blockDim.x + threadIdx.x;
  if (i >= n4) return;
  float4 a = ((const float4*)out)[i];
  float4 b = ((const float4*)p0)[i];
  float4 c = ((const float4*)p1)[i];
  a.x += b.x + c.x; a.y += b.y + c.y; a.z += b.z + c.z; a.w += b.w + c.w;
  ((float4*)out)[i] = a;
}

// ---------------------------------------------------------------------------
extern "C" void kernel_launch(void* const* d_in, const int* in_sizes, int n_in,
                              void* d_out, int out_size, void* d_ws, size_t ws_size,
                              hipStream_t stream) {
  const float* x  = (const float*)d_in[0];  // [T][D]
  const float* rw = (const float*)d_in[1];  // [16][D]
  const float* gw = (const float*)d_in[2];  // [16][D][F]
  const float* uw = (const float*)d_in[3];  // [16][D][F]
  const float* dw = (const float*)d_in[4];  // [16][F][D]
  const float* sg = (const float*)d_in[5];  // [D][F]
  const float* su = (const float*)d_in[6];  // [D][F]
  const float* sd = (const float*)d_in[7];  // [F][D]
  float* out = (float*)d_out;
  // d_in[8] = top_k (hardcoded 8)

  // Workspace layout (~134 MiB). p0 aliases xb+wg, p1 aliases wu (dead after stage A).
  char* ws = (char*)d_ws;
  size_t off = 0;
  __hip_bfloat16* xb = (__hip_bfloat16*)(ws + off); off += (size_t)T_TOK * DDIM * 2;
  __hip_bfloat16* wg = (__hip_bfloat16*)(ws + off); off += (size_t)NE17 * FDIM * DDIM * 2;
  __hip_bfloat16* wu = (__hip_bfloat16*)(ws + off);
  const size_t wu_off = off;                         off += (size_t)NE17 * FDIM * DDIM * 2;
  __hip_bfloat16* wd = (__hip_bfloat16*)(ws + off);  off += (size_t)NE17 * DDIM * FDIM * 2;
  __hip_bfloat16* H  = (__hip_bfloat16*)(ws + off);
  const size_t H_bytes = (size_t)NE17 * T_TOK * FDIM * 2; off += H_bytes;
  float* cw      = (float*)(ws + off); off += (size_t)T_TOK * 16 * 4;
  int*   cnt     = (int*)(ws + off);   off += 32 * 4;
  int*   padBase = (int*)(ws + off);   off += 32 * 4;
  int*   tileE   = (int*)(ws + off);   off += MAXTILES * 4;
  int*   tileBase= (int*)(ws + off);   off += MAXTILES * 4;
  int*   perm    = (int*)(ws + off);   off += 40960 * 4;
  float* rowW    = (float*)(ws + off); off += 40960 * 4;
  float* p0 = (float*)ws;              // 16.8 MB over xb(8.4)+wg(17.8)
  float* p1 = (float*)(ws + wu_off);   // 16.8 MB over wu(17.8)
  (void)ws_size; (void)in_sizes; (void)n_in; (void)out_size;

  // H must be zero for non-selected (expert,token) pairs (stage B reads dense H)
  hipMemsetAsync(H, 0, H_bytes, stream);

  convert_router<<<T_TOK, 64, 0, stream>>>(x, rw, xb, cw);
  dim3 tb(64, 4);
  transpose_convert2<<<dim3(FDIM / 64, DDIM / 64, NE17), tb, 0, stream>>>(
      gw, sg, uw, su, wg, wu, DDIM, FDIM);
  transpose_convert<<<dim3(DDIM / 64, FDIM / 64, NE17), tb, 0, stream>>>(dw, sd, wd, FDIM, DDIM);

  moe_count<<<NEXP, 64, 0, stream>>>(cw, cnt);
  moe_scan<<<1, 64, 0, stream>>>(cnt, padBase, tileE, tileBase);
  moe_place<<<NE17, 64, 0, stream>>>(cw, cnt, padBase, perm, rowW);

  moe_stageA_grouped<<<dim3(MAXTILES, FDIM / 128), 256, 0, stream>>>(
      xb, wg, wu, perm, rowW, tileE, tileBase, H);
  moe_stageB_split<<<dim3(256, 3), 256, 0, stream>>>(H, wd, out, p0, p1);
  add_partial<<<(T_TOK * DDIM / 4 + 255) / 256, 256, 0, stream>>>(out, p0, p1, T_TOK * DDIM / 4);
}

// Round 6
// 264.447 us; speedup vs baseline: 2.1610x; 2.1610x over previous
//
#include <hip/hip_runtime.h>
#include <hip/hip_bf16.h>

// Problem constants (from reference): B=2, S=2048 -> T=4096 tokens
#define T_TOK 4096
#define DDIM  1024
#define FDIM  512
#define NEXP  16
#define NE17  17       // 16 experts + shared expert as expert 16 (cw=1)
#define MAXTILES 304   // 272 max expert row-tiles + 32 shared; 304 = 8*38 (XCD-exact)

using bf16x8 = __attribute__((ext_vector_type(8))) __bf16;
using f32x4  = __attribute__((ext_vector_type(4))) float;

// ---------------------------------------------------------------------------
// async global->LDS, 16B per lane. LDS dest = wave-uniform base + lane*16;
// global source is per-lane (gather-capable).
__device__ __forceinline__ void gload_lds16(const void* g, void* l) {
  __builtin_amdgcn_global_load_lds(
      (const __attribute__((address_space(1))) void*)g,
      (__attribute__((address_space(3))) void*)l, 16, 0, 0);
}

// XOR-swizzled ds_read_b128 of one MFMA fragment (8 bf16 along K).
// All LDS tiles are [rows][64] bf16 => 128B rows. chunk = 16B unit along K.
__device__ __forceinline__ bf16x8 frag_ld(const __hip_bfloat16* smem, int row, int chunk) {
  const char* p = (const char*)smem + row * 128 + ((chunk ^ (row & 7)) << 4);
  return *(const bf16x8*)p;
}

// ---------------------------------------------------------------------------
// Fused x->bf16 convert + router. One wave per token; x row read ONCE into
// registers, used for both the bf16 store and the 16 router dot products.
// Top-8 via lane-parallel rank (tie-break lower index == jax.lax.top_k).
__global__ void convert_router(const float* __restrict__ x, const float* __restrict__ rw,
                               __hip_bfloat16* __restrict__ xb, float* __restrict__ cw) {
  const int t = blockIdx.x;
  const int lane = threadIdx.x;  // 64
  const float4* xrow = (const float4*)(x + (size_t)t * DDIM);
  float4 v[4];
#pragma unroll
  for (int c = 0; c < 4; c++) v[c] = xrow[lane + 64 * c];
  // bf16 convert + store (8B per lane per chunk, coalesced)
  __hip_bfloat16* orow = xb + (size_t)t * DDIM;
#pragma unroll
  for (int c = 0; c < 4; c++) {
    __hip_bfloat16 h[4] = {__float2bfloat16(v[c].x), __float2bfloat16(v[c].y),
                           __float2bfloat16(v[c].z), __float2bfloat16(v[c].w)};
    *(uint2*)(orow + (lane + 64 * c) * 4) = *(const uint2*)h;
  }
  // router logits (fp32, exact as reference)
  const float4* rw4 = (const float4*)rw;
  float myLg = 0.f;
#pragma unroll
  for (int e = 0; e < NEXP; e++) {
    float p = 0.f;
#pragma unroll
    for (int c = 0; c < 4; c++) {
      const float4 r = rw4[e * 256 + lane + 64 * c];
      p += v[c].x * r.x + v[c].y * r.y + v[c].z * r.z + v[c].w * r.w;
    }
#pragma unroll
    for (int off = 32; off > 0; off >>= 1) p += __shfl_xor(p, off);
    if (lane == e) myLg = p;  // lane e keeps logit e (all lanes have the sum)
  }
  // max over lanes 0..15 (xor 8/4/2/1 closed within the 16-lane group)
  float m = myLg;
#pragma unroll
  for (int off = 8; off > 0; off >>= 1) m = fmaxf(m, __shfl_xor(m, off));
  const float pe = __expf(myLg - m);
  int rank = 0;
#pragma unroll
  for (int j = 0; j < NEXP; j++) {
    const float pj = __shfl(pe, j);
    rank += ((pj > pe) || (pj == pe && j < lane)) ? 1 : 0;
  }
  const bool sel = (lane < NEXP) && (rank < 8);
  float ss = sel ? pe : 0.f;
#pragma unroll
  for (int off = 8; off > 0; off >>= 1) ss += __shfl_xor(ss, off);
  if (lane < NEXP) cw[(size_t)t * NEXP + lane] = sel ? pe / ss : 0.f;
}

// ---------------------------------------------------------------------------
// Token->expert grouping (deterministic): count, scan+tile-map, place.
__global__ void moe_count(const float* __restrict__ cw, int* __restrict__ cnt) {
  const int e = blockIdx.x;  // 0..15
  const int lane = threadIdx.x;
  int c = 0;
  for (int t = lane; t < T_TOK; t += 64) c += (cw[(size_t)t * 16 + e] > 0.f) ? 1 : 0;
#pragma unroll
  for (int off = 32; off > 0; off >>= 1) c += __shfl_xor(c, off);
  if (lane == 0) cnt[e] = c;
}

__global__ void moe_scan(const int* __restrict__ cnt, int* __restrict__ padBase,
                         int* __restrict__ tileE, int* __restrict__ tileBase) {
  if (threadIdx.x != 0) return;
  int base = 0, tile = 0;
  for (int e = 0; e < 16; e++) {
    padBase[e] = base;
    const int nt = (cnt[e] + 127) >> 7;
    for (int i = 0; i < nt; i++) { tileE[tile] = e; tileBase[tile] = base + (i << 7); tile++; }
    base += nt << 7;
  }
  padBase[16] = base;  // shared-expert group base
  for (int i = 0; i < 32; i++) { tileE[tile] = 16; tileBase[tile] = base + (i << 7); tile++; }
  for (; tile < MAXTILES; tile++) tileE[tile] = -1;
}

__global__ void moe_place(const float* __restrict__ cw, const int* __restrict__ cnt,
                          const int* __restrict__ padBase,
                          int* __restrict__ perm, float* __restrict__ rowW) {
  const int e = blockIdx.x;  // 0..16
  const int lane = threadIdx.x;  // one wave
  const int base = padBase[e];
  if (e == 16) {  // shared expert: identity order, weight 1
    for (int t = lane; t < T_TOK; t += 64) { perm[base + t] = t; rowW[base + t] = 1.0f; }
    return;
  }
  int running = 0;
  for (int t0 = 0; t0 < T_TOK; t0 += 64) {
    const int t = t0 + lane;
    const float w = cw[(size_t)t * 16 + e];
    const unsigned long long m = __ballot(w > 0.f);
    if (w > 0.f) {
      const int r = base + running + __popcll(m & ((1ull << lane) - 1ull));
      perm[r] = t; rowW[r] = w;
    }
    running += __popcll(m);
  }
  const int padded = ((cnt[e] + 127) >> 7) << 7;  // cnt[e] == running
  for (int i = running + lane; i < padded; i += 64) { perm[base + i] = -1; rowW[base + i] = 0.f; }
}

// ---------------------------------------------------------------------------
// Transpose-convert gate+up together: in [R][C] fp32 x2 -> out [C][R] bf16 x2.
__global__ __launch_bounds__(256, 4) void transpose_convert2(
    const float* __restrict__ srcMainA, const float* __restrict__ srcSharedA,
    const float* __restrict__ srcMainB, const float* __restrict__ srcSharedB,
    __hip_bfloat16* __restrict__ dstA, __hip_bfloat16* __restrict__ dstB, int R, int C) {
  const int e = blockIdx.z;
  const float* srcA = (e < NEXP) ? srcMainA + (size_t)e * R * C : srcSharedA;
  const float* srcB = (e < NEXP) ? srcMainB + (size_t)e * R * C : srcSharedB;
  __hip_bfloat16* outA = dstA + (size_t)e * R * C;
  __hip_bfloat16* outB = dstB + (size_t)e * R * C;
  __shared__ float tA[64][65];
  __shared__ float tB[64][65];
  const int c0 = blockIdx.x * 64, r0 = blockIdx.y * 64;
  const int tx = threadIdx.x, ty = threadIdx.y;  // 64 x 4
#pragma unroll
  for (int i = 0; i < 64; i += 4) {
    tA[ty + i][tx] = srcA[(size_t)(r0 + ty + i) * C + c0 + tx];
    tB[ty + i][tx] = srcB[(size_t)(r0 + ty + i) * C + c0 + tx];
  }
  __syncthreads();
#pragma unroll
  for (int i = 0; i < 64; i += 4) {
    outA[(size_t)(c0 + ty + i) * R + r0 + tx] = __float2bfloat16(tA[tx][ty + i]);
    outB[(size_t)(c0 + ty + i) * R + r0 + tx] = __float2bfloat16(tB[tx][ty + i]);
  }
}

// Single transpose-convert (down + sd)
__global__ __launch_bounds__(256, 4) void transpose_convert(
    const float* __restrict__ srcMain, const float* __restrict__ srcShared,
    __hip_bfloat16* __restrict__ dst, int R, int C) {
  const int e = blockIdx.z;
  const float* src = (e < NEXP) ? srcMain + (size_t)e * R * C : srcShared;
  __hip_bfloat16* out = dst + (size_t)e * R * C;
  __shared__ float tile[64][65];
  const int c0 = blockIdx.x * 64, r0 = blockIdx.y * 64;
  const int tx = threadIdx.x, ty = threadIdx.y;  // 64 x 4
#pragma unroll
  for (int i = 0; i < 64; i += 4)
    tile[ty + i][tx] = src[(size_t)(r0 + ty + i) * C + c0 + tx];
  __syncthreads();
#pragma unroll
  for (int i = 0; i < 64; i += 4)
    out[(size_t)(c0 + ty + i) * R + r0 + tx] = __float2bfloat16(tile[tx][ty + i]);
}

// ---------------------------------------------------------------------------
// Stage A v3 (grouped/sparse, f-width 64): per (expert row-tile of 128 gathered
// tokens) x (64 f-cols): G = Xg @ Wg[e], U = Xg @ Wu[e] dual-acc, shared X tile.
// Per-wave output 64x32 dual -> acc = 64 regs (fits 3 waves/SIMD: ~150 total).
// H[e][tok][f] = silu(G)*U * rowW. Pad rows (perm<0) load token 0, store nothing.
__global__ __launch_bounds__(256, 3) void moe_stageA_grouped(
    const __hip_bfloat16* __restrict__ xb,   // [T][D]
    const __hip_bfloat16* __restrict__ wg,   // [17][F][D]
    const __hip_bfloat16* __restrict__ wu,   // [17][F][D]
    const int* __restrict__ perm, const float* __restrict__ rowW,
    const int* __restrict__ tileE, const int* __restrict__ tileBase,
    __hip_bfloat16* __restrict__ H)          // [17][T][F] (pre-zeroed)
{
  __shared__ __hip_bfloat16 sA[128 * 64];   // 16 KB: X tile (128 gathered rows)
  __shared__ __hip_bfloat16 sG[64 * 64];    // 8 KB: Wg tile (64 f-rows)
  __shared__ __hip_bfloat16 sU[64 * 64];    // 8 KB: Wu tile
  __shared__ int   sTok[128];
  __shared__ float sW[128];

  // XCD-chunked swizzle: 304 = 8*38; XCD k gets contiguous tiles [38k,38k+38)
  const int tile = (blockIdx.x & 7) * (MAXTILES / 8) + (blockIdx.x >> 3);
  const int e = tileE[tile];
  if (e < 0) return;
  const int rbase = tileBase[tile];
  const int f0 = blockIdx.y * 64;
  const int tid = threadIdx.x;
  const int wid = tid >> 6, lane = tid & 63;
  const int wr = (wid >> 1) * 64, wc = (wid & 1) * 32;  // wave tile 64x32 (dual)
  const int rl = lane >> 3, cl = lane & 7;

  if (tid < 128) { const int r = rbase + tid; sTok[tid] = perm[r]; sW[tid] = rowW[r]; }
  __syncthreads();

  const __hip_bfloat16* wgE = wg + (size_t)e * FDIM * DDIM;
  const __hip_bfloat16* wuE = wu + (size_t)e * FDIM * DDIM;

  // hoisted per-lane staging pointers (k0-invariant part)
  // sA: wave w stages rows [32w,32w+32) -> 4 gloads; sG/sU: rows [16w,16w+16) -> 2 each
  const char* pA[4]; const char* pG[2]; const char* pU[2]; int ldsA[4], ldsB[2];
#pragma unroll
  for (int i = 0; i < 4; i++) {
    const int row = 32 * wid + 8 * i + rl;
    const int sw = (cl ^ (row & 7)) << 3;  // element offset of swizzled 16B chunk
    int tk = sTok[row]; if (tk < 0) tk = 0;
    pA[i] = (const char*)(xb + (size_t)tk * DDIM + sw);
    ldsA[i] = (32 * wid + 8 * i) * 64;
  }
#pragma unroll
  for (int i = 0; i < 2; i++) {
    const int row = 16 * wid + 8 * i + rl;
    const int sw = (cl ^ (row & 7)) << 3;
    pG[i] = (const char*)(wgE + (size_t)(f0 + row) * DDIM + sw);
    pU[i] = (const char*)(wuE + (size_t)(f0 + row) * DDIM + sw);
    ldsB[i] = (16 * wid + 8 * i) * 64;
  }

  const f32x4 vzero = {0.f, 0.f, 0.f, 0.f};
  f32x4 accG[4][2], accU[4][2];
#pragma unroll
  for (int m = 0; m < 4; m++)
#pragma unroll
    for (int n = 0; n < 2; n++) { accG[m][n] = vzero; accU[m][n] = vzero; }

  for (int k0 = 0; k0 < DDIM; k0 += 64) {
    __syncthreads();  // previous iter's reads done before overwrite
#pragma unroll
    for (int i = 0; i < 4; i++) gload_lds16(pA[i] + (size_t)k0 * 2, &sA[ldsA[i]]);
#pragma unroll
    for (int i = 0; i < 2; i++) {
      gload_lds16(pG[i] + (size_t)k0 * 2, &sG[ldsB[i]]);
      gload_lds16(pU[i] + (size_t)k0 * 2, &sU[ldsB[i]]);
    }
    __syncthreads();  // drains vmcnt -> staged data visible
#pragma unroll
    for (int kk = 0; kk < 2; kk++) {
      const int kch = kk * 4 + (lane >> 4);
      bf16x8 af[4], bg[2], bu[2];
#pragma unroll
      for (int m = 0; m < 4; m++) af[m] = frag_ld(sA, wr + m * 16 + (lane & 15), kch);
#pragma unroll
      for (int n = 0; n < 2; n++) {
        bg[n] = frag_ld(sG, wc + n * 16 + (lane & 15), kch);
        bu[n] = frag_ld(sU, wc + n * 16 + (lane & 15), kch);
      }
#pragma unroll
      for (int m = 0; m < 4; m++)
#pragma unroll
        for (int n = 0; n < 2; n++) {
          accG[m][n] = __builtin_amdgcn_mfma_f32_16x16x32_bf16(af[m], bg[n], accG[m][n], 0, 0, 0);
          accU[m][n] = __builtin_amdgcn_mfma_f32_16x16x32_bf16(af[m], bu[n], accU[m][n], 0, 0, 0);
        }
    }
  }
  // epilogue: h = silu(g)*u*rowW -> H[e][tok][:]; pad rows store nothing
  const int lr = (lane >> 4) * 4, lc = lane & 15;
#pragma unroll
  for (int m = 0; m < 4; m++)
#pragma unroll
    for (int n = 0; n < 2; n++)
#pragma unroll
      for (int j = 0; j < 4; j++) {
        const int r = wr + m * 16 + lr + j;
        const int c = wc + n * 16 + lc;
        const int tok = sTok[r];
        if (tok >= 0) {
          const float g = accG[m][n][j], u = accU[m][n][j];
          const float h = (g / (1.0f + __expf(-g))) * u * sW[r];
          H[((size_t)e * T_TOK + tok) * FDIM + f0 + c] = __float2bfloat16(h);
        }
      }
}

// ---------------------------------------------------------------------------
// Stage B (K-split x3, single-buffered m97 structure): out[t][d] = sum over
// K=17*512 of H[e][t][f]*Wd_t[e][d][f]. 32KB LDS -> 4 blocks/CU for TLP.
// split 0 -> p0, split 1 -> p1, split 2 -> out; then out += p0 + p1.
__global__ __launch_bounds__(256, 4) void moe_stageB_split(
    const __hip_bfloat16* __restrict__ H,    // [17][T][F]
    const __hip_bfloat16* __restrict__ wd,   // [17][D][F]
    float* __restrict__ out,                 // [T][D]
    float* __restrict__ p0, float* __restrict__ p1)
{
  __shared__ __hip_bfloat16 sA[128 * 64];
  __shared__ __hip_bfloat16 sB[128 * 64];

  // XCD-chunked mapping: XCD k owns t-tiles [4k,4k+4) x all 8 d-tiles
  const int id = blockIdx.x;            // 0..255, id&7 = XCD (round-robin dispatch)
  const int xcd = id & 7, slot = id >> 3;
  const int t0 = (xcd * 4 + (slot & 3)) * 128;
  const int d0 = (slot >> 2) * 128;
  const int tid = threadIdx.x, wid = tid >> 6, lane = tid & 63;
  const int wr = (wid >> 1) * 64, wc = (wid & 1) * 64;  // wave tile 64x64
  const int rl = lane >> 3, cl = lane & 7;

  // hoisted per-lane staging offsets (k0-invariant row part)
  size_t offA[4], offB[4]; int ldsO[4];
#pragma unroll
  for (int i = 0; i < 4; i++) {
    const int row = 32 * wid + 8 * i + rl;
    const int sw = (cl ^ (row & 7)) << 3;
    offA[i] = (size_t)(t0 + row) * FDIM + sw;
    offB[i] = (size_t)(d0 + row) * FDIM + sw;
    ldsO[i] = (32 * wid + 8 * i) * 64;
  }

  const f32x4 vzero = {0.f, 0.f, 0.f, 0.f};
  f32x4 acc[4][4];
#pragma unroll
  for (int m = 0; m < 4; m++)
#pragma unroll
    for (int n = 0; n < 4; n++) acc[m][n] = vzero;

  const int NKS = NE17 * FDIM / 64;  // 136 total K-steps
  const int split = blockIdx.y;      // 0..2 -> steps [45,45,46]
  const int ks0 = (split * NKS) / 3, ks1 = ((split + 1) * NKS) / 3;

  for (int ks = ks0; ks < ks1; ks++) {
    const int k0 = ks * 64;
    const int ee = k0 >> 9, ff = k0 & 511;  // FDIM=512 | 64 => no straddle
    const size_t sOffA = (size_t)ee * T_TOK * FDIM + ff;
    const size_t sOffB = (size_t)ee * DDIM * FDIM + ff;
    __syncthreads();  // previous iter's reads done before overwrite
#pragma unroll
    for (int i = 0; i < 4; i++) {
      gload_lds16(H  + sOffA + offA[i], &sA[ldsO[i]]);
      gload_lds16(wd + sOffB + offB[i], &sB[ldsO[i]]);
    }
    __syncthreads();  // drains vmcnt: staged data visible
#pragma unroll
    for (int kk = 0; kk < 2; kk++) {
      const int kch = kk * 4 + (lane >> 4);
      bf16x8 af[4], bb[4];
#pragma unroll
      for (int m = 0; m < 4; m++) af[m] = frag_ld(sA, wr + m * 16 + (lane & 15), kch);
#pragma unroll
      for (int n = 0; n < 4; n++) bb[n] = frag_ld(sB, wc + n * 16 + (lane & 15), kch);
#pragma unroll
      for (int m = 0; m < 4; m++)
#pragma unroll
        for (int n = 0; n < 4; n++)
          acc[m][n] = __builtin_amdgcn_mfma_f32_16x16x32_bf16(af[m], bb[n], acc[m][n], 0, 0, 0);
    }
  }
  float* dst = (split == 0) ? p0 : (split == 1) ? p1 : out;
  const int lr = (lane >> 4) * 4, lc = lane & 15;
#pragma unroll
  for (int m = 0; m < 4; m++)
#pragma unroll
    for (int n = 0; n < 4; n++)
#pragma unroll
      for (int j = 0; j < 4; j++)
        dst[(size_t)(t0 + wr + m * 16 + lr + j) * DDIM + d0 + wc + n * 16 + lc] = acc[m][n][j];
}

// out += p0 + p1 (float4)
__global__ void add_partial(float* __restrict__ out, const float* __restrict__ p0,
                            const float* __restrict__ p1, int n4) {
  int i = blockIdx.x * blockDim.x + threadIdx.x;
  if (i >= n4) return;
  float4 a = ((const float4*)out)[i];
  float4 b = ((const float4*)p0)[i];
  float4 c = ((const float4*)p1)[i];
  a.x += b.x + c.x; a.y += b.y + c.y; a.z += b.z + c.z; a.w += b.w + c.w;
  ((float4*)out)[i] = a;
}

// ---------------------------------------------------------------------------
extern "C" void kernel_launch(void* const* d_in, const int* in_sizes, int n_in,
                              void* d_out, int out_size, void* d_ws, size_t ws_size,
                              hipStream_t stream) {
  const float* x  = (const float*)d_in[0];  // [T][D]
  const float* rw = (const float*)d_in[1];  // [16][D]
  const float* gw = (const float*)d_in[2];  // [16][D][F]
  const float* uw = (const float*)d_in[3];  // [16][D][F]
  const float* dw = (const float*)d_in[4];  // [16][F][D]
  const float* sg = (const float*)d_in[5];  // [D][F]
  const float* su = (const float*)d_in[6];  // [D][F]
  const float* sd = (const float*)d_in[7];  // [F][D]
  float* out = (float*)d_out;
  // d_in[8] = top_k (hardcoded 8)

  // Workspace layout (~134 MiB). p0 aliases xb+wg, p1 aliases wu (dead after stage A).
  char* ws = (char*)d_ws;
  size_t off = 0;
  __hip_bfloat16* xb = (__hip_bfloat16*)(ws + off); off += (size_t)T_TOK * DDIM * 2;
  __hip_bfloat16* wg = (__hip_bfloat16*)(ws + off); off += (size_t)NE17 * FDIM * DDIM * 2;
  __hip_bfloat16* wu = (__hip_bfloat16*)(ws + off);
  const size_t wu_off = off;                         off += (size_t)NE17 * FDIM * DDIM * 2;
  __hip_bfloat16* wd = (__hip_bfloat16*)(ws + off);  off += (size_t)NE17 * DDIM * FDIM * 2;
  __hip_bfloat16* H  = (__hip_bfloat16*)(ws + off);
  const size_t H_bytes = (size_t)NE17 * T_TOK * FDIM * 2; off += H_bytes;
  float* cw      = (float*)(ws + off); off += (size_t)T_TOK * 16 * 4;
  int*   cnt     = (int*)(ws + off);   off += 32 * 4;
  int*   padBase = (int*)(ws + off);   off += 32 * 4;
  int*   tileE   = (int*)(ws + off);   off += MAXTILES * 4;
  int*   tileBase= (int*)(ws + off);   off += MAXTILES * 4;
  int*   perm    = (int*)(ws + off);   off += 40960 * 4;
  float* rowW    = (float*)(ws + off); off += 40960 * 4;
  float* p0 = (float*)ws;              // 16.8 MB over xb(8.4)+wg(17.8)
  float* p1 = (float*)(ws + wu_off);   // 16.8 MB over wu(17.8)
  (void)ws_size; (void)in_sizes; (void)n_in; (void)out_size;

  // H must be zero for non-selected (expert,token) pairs (stage B reads dense H)
  hipMemsetAsync(H, 0, H_bytes, stream);

  convert_router<<<T_TOK, 64, 0, stream>>>(x, rw, xb, cw);
  dim3 tb(64, 4);
  transpose_convert2<<<dim3(FDIM / 64, DDIM / 64, NE17), tb, 0, stream>>>(
      gw, sg, uw, su, wg, wu, DDIM, FDIM);
  transpose_convert<<<dim3(DDIM / 64, FDIM / 64, NE17), tb, 0, stream>>>(dw, sd, wd, FDIM, DDIM);

  moe_count<<<NEXP, 64, 0, stream>>>(cw, cnt);
  moe_scan<<<1, 64, 0, stream>>>(cnt, padBase, tileE, tileBase);
  moe_place<<<NE17, 64, 0, stream>>>(cw, cnt, padBase, perm, rowW);

  moe_stageA_grouped<<<dim3(MAXTILES, FDIM / 64), 256, 0, stream>>>(
      xb, wg, wu, perm, rowW, tileE, tileBase, H);
  moe_stageB_split<<<dim3(256, 3), 256, 0, stream>>>(H, wd, out, p0, p1);
  add_partial<<<(T_TOK * DDIM / 4 + 255) / 256, 256, 0, stream>>>(out, p0, p1, T_TOK * DDIM / 4);
}